// Round 11
// baseline (290.478 us; speedup 1.0000x reference)
//
#include <hip/hip_runtime.h>

typedef __attribute__((ext_vector_type(8))) short bf16x8;
typedef __attribute__((ext_vector_type(8))) unsigned short ushort8_t;
typedef __attribute__((ext_vector_type(4))) float f32x4;

__device__ __forceinline__ unsigned short f2bf(float f) {
    unsigned int x = __float_as_uint(f);
    unsigned int r = x + 0x7fffu + ((x >> 16) & 1u);
    return (unsigned short)(r >> 16);
}
__device__ __forceinline__ float bf2f(unsigned short u) {
    return __uint_as_float(((unsigned int)u) << 16);
}
// raw v_exp_f32 — no libm denormal fixup (precise exp2f cost r7/r8 ~17us in agg512)
__device__ __forceinline__ float fexp2(float x) { return __builtin_amdgcn_exp2f(x); }

#define LOG2E 1.44269504089f

// ---------------- fused prologue: edge-count + x cast + both weight packs ----------------
__global__ __launch_bounds__(256) void prep_kernel(
    const int* __restrict__ dst, int E, int* __restrict__ counts,
    const float* __restrict__ x, unsigned short* __restrict__ xb, size_t nx4,
    const float* __restrict__ W1l, const float* __restrict__ W1r, unsigned short* __restrict__ Bt1,
    const float* __restrict__ W2l, const float* __restrict__ W2r, unsigned short* __restrict__ Bt2) {
    int i = blockIdx.x * 256 + threadIdx.x;
    int total = gridDim.x * 256;
    if (i < E) atomicAdd(&counts[dst[i]], 1);
    for (size_t j = i; j < nx4; j += total) {
        float4 v = *(const float4*)(x + j * 4);
        ushort4 o;
        o.x = f2bf(v.x); o.y = f2bf(v.y); o.z = f2bf(v.z); o.w = f2bf(v.w);
        *(ushort4*)(xb + j * 4) = o;
    }
    if (i < 512 * 256) {
        int nn = i >> 8, k = i & 255;
        float v = (k < 128) ? W1l[(size_t)k * 512 + nn] : W1r[(size_t)(k - 128) * 512 + nn];
        Bt1[i] = f2bf(v);
    }
    if (i < 256 * 1024) {
        int nn = i >> 10, k = i & 1023;
        float v = (k < 512) ? W2l[(size_t)k * 256 + nn] : W2r[(size_t)(k - 512) * 256 + nn];
        Bt2[i] = f2bf(v);
    }
}

// also zeroes cnt after reading (cursor reuse, saves a memset dispatch)
template <int CHUNK>
__global__ __launch_bounds__(1024) void scan_kernel(int* __restrict__ cnt,
                                                    int* __restrict__ off, int n) {
    __shared__ int s[1024];
    int tid = threadIdx.x;
    int base = tid * CHUNK;
    int loc[CHUNK];
    int sum = 0;
#pragma unroll
    for (int i = 0; i < CHUNK; ++i) {
        int idx = base + i;
        int v = 0;
        if (idx < n) { v = cnt[idx]; cnt[idx] = 0; }
        sum += v;
        loc[i] = sum;
    }
    s[tid] = sum;
    __syncthreads();
    for (int d = 1; d < 1024; d <<= 1) {
        int t = (tid >= d) ? s[tid - d] : 0;
        __syncthreads();
        s[tid] += t;
        __syncthreads();
    }
    int prev = (tid > 0) ? s[tid - 1] : 0;
    if (tid == 0) off[0] = 0;
#pragma unroll
    for (int i = 0; i < CHUNK; ++i) {
        int idx = base + i;
        if (idx < n) off[idx + 1] = prev + loc[i];
    }
}

__global__ void fill_kernel(const int* __restrict__ src, const int* __restrict__ dst, int E,
                            const int* __restrict__ off, int* __restrict__ cursor,
                            int* __restrict__ srcs) {
    int i = blockIdx.x * 256 + threadIdx.x;
    if (i < E) {
        int d = dst[i];
        int p = atomicAdd(&cursor[d], 1);
        srcs[off[d] + p] = src[i];
    }
}

// ---------------- softmax aggregation, wave-per-node, C=512 (8 ch/lane) ----------------
// 2-edge unroll (28 VGPR, ~55% occupancy): deeper unroll regressed (r7: 52 VGPR, 30% occ).
__global__ __launch_bounds__(256) void agg512(const unsigned short* __restrict__ h,
                                              const float* __restrict__ t,
                                              const int* __restrict__ off,
                                              const int* __restrict__ srcs,
                                              unsigned short* __restrict__ agg, int n) {
    int wid = threadIdx.x >> 6, lane = threadIdx.x & 63;
    int node = blockIdx.x * 4 + wid;
    if (node >= n) return;
    int beg = off[node], end = off[node + 1];
    int col = lane * 8;
    float tc[8], sE[8], sW[8];
#pragma unroll
    for (int i = 0; i < 8; ++i) { tc[i] = t[col + i] * LOG2E; sE[i] = 0.f; sW[i] = 0.f; }
#define P8(u)                                       \
    _Pragma("unroll") for (int i = 0; i < 8; ++i) { \
        float v = bf2f(u[i]);                       \
        float wv = fexp2(v * tc[i]);                \
        sE[i] += wv; sW[i] += v * wv;               \
    }
    int e = beg;
    for (; e + 2 <= end; e += 2) {
        int s0 = srcs[e], s1 = srcs[e + 1];
        ushort8_t u0 = *(const ushort8_t*)(h + (size_t)s0 * 512 + col);
        ushort8_t u1 = *(const ushort8_t*)(h + (size_t)s1 * 512 + col);
        P8(u0) P8(u1)
    }
    if (e < end) {
        int s0 = srcs[e];
        ushort8_t u0 = *(const ushort8_t*)(h + (size_t)s0 * 512 + col);
        P8(u0)
    }
#undef P8
    ushort8_t o;
#pragma unroll
    for (int i = 0; i < 8; ++i) o[i] = f2bf((end > beg) ? (sW[i] / sE[i]) : 0.f);
    *(ushort8_t*)(agg + (size_t)node * 512 + col) = o;
}

// ---------------- softmax aggregation, wave-per-node, C=128 (2 ch/lane) ----------------
__global__ __launch_bounds__(256) void agg128(const unsigned short* __restrict__ h,
                                              const float* __restrict__ t,
                                              const int* __restrict__ off,
                                              const int* __restrict__ srcs,
                                              unsigned short* __restrict__ agg, int n) {
    int wid = threadIdx.x >> 6, lane = threadIdx.x & 63;
    int node = blockIdx.x * 4 + wid;
    if (node >= n) return;
    int beg = off[node], end = off[node + 1];
    int col = lane * 2;
    float t0 = t[col] * LOG2E, t1 = t[col + 1] * LOG2E;
    float e0 = 0.f, e1 = 0.f, w0 = 0.f, w1 = 0.f;
#define P2(u)                                          \
    {                                                  \
        float a = bf2f(u.x), b = bf2f(u.y);            \
        float xa = fexp2(a * t0), xb = fexp2(b * t1);  \
        e0 += xa; e1 += xb; w0 += a * xa; w1 += b * xb; \
    }
    int e = beg;
    for (; e + 4 <= end; e += 4) {
        ushort2 u0 = *(const ushort2*)(h + (size_t)srcs[e] * 128 + col);
        ushort2 u1 = *(const ushort2*)(h + (size_t)srcs[e + 1] * 128 + col);
        ushort2 u2 = *(const ushort2*)(h + (size_t)srcs[e + 2] * 128 + col);
        ushort2 u3 = *(const ushort2*)(h + (size_t)srcs[e + 3] * 128 + col);
        P2(u0) P2(u1) P2(u2) P2(u3)
    }
    for (; e < end; ++e) {
        ushort2 u0 = *(const ushort2*)(h + (size_t)srcs[e] * 128 + col);
        P2(u0)
    }
#undef P2
    ushort2 o;
    o.x = f2bf((end > beg) ? (w0 / e0) : 0.f);
    o.y = f2bf((end > beg) ? (w1 / e1) : 0.f);
    *(ushort2*)(agg + (size_t)node * 128 + col) = o;
}

// ---------------- fused dual bf16 MFMA GEMM + fp64 stats partials ----------------
// 64x256 tile, 256 threads (4 waves = 4 column quadrants of 64x64).
// Small blocks -> 313/626-block grids fill all 256 CUs (old 512-thr/157-block grid
// left ~100 CUs idle on gemm2). reg-staged, pad-40 LDS (2-way aliasing = free).
__global__ __launch_bounds__(256) void gemm_dual_mfma3(
    const unsigned short* __restrict__ A1, const unsigned short* __restrict__ A2,
    const unsigned short* __restrict__ Bt,
    unsigned short* __restrict__ Cb, double* __restrict__ part,
    int M, int N, int K1, int K2) {
    const int Kc = K1 + K2;
    __shared__ unsigned short As[64 * 40];
    __shared__ unsigned short Bs[256 * 40];
    __shared__ double rs[256], rs2[256];
    int tid = threadIdx.x;
    int lane = tid & 63, w = tid >> 6;  // w = column quadrant
    int m0 = blockIdx.y * 64, n0 = blockIdx.x * 256;
    f32x4 acc[4][4] = {};
    int kg = lane >> 4, lr = lane & 15;

    for (int k0 = 0; k0 < Kc; k0 += 32) {
        const unsigned short* Asrc;
        int kk, Ksrc;
        if (k0 < K1) { Asrc = A1; kk = k0; Ksrc = K1; }
        else         { Asrc = A2; kk = k0 - K1; Ksrc = K2; }
        // stage A: 64 rows x 32 k; one ushort8 per thread
        {
            int r = tid >> 2, ch = tid & 3;
            int gr = m0 + r;
            ushort8_t v = {0, 0, 0, 0, 0, 0, 0, 0};
            if (gr < M) v = *(const ushort8_t*)(Asrc + (size_t)gr * Ksrc + kk + ch * 8);
            *(ushort8_t*)&As[r * 40 + ch * 8] = v;
        }
        // stage B: 256 cols x 32 k; four ushort8 per thread
#pragma unroll
        for (int it = 0; it < 4; ++it) {
            int idx = tid + it * 256;
            int r = idx >> 2, ch = idx & 3;
            const unsigned short* srcp = Bt + (size_t)(n0 + r) * Kc + k0 + ch * 8;
            *(ushort8_t*)&Bs[r * 40 + ch * 8] = *(const ushort8_t*)srcp;
        }
        __syncthreads();
        bf16x8 a[4], b[4];
#pragma unroll
        for (int i = 0; i < 4; ++i)
            a[i] = *(bf16x8*)&As[(i * 16 + lr) * 40 + kg * 8];
#pragma unroll
        for (int j = 0; j < 4; ++j)
            b[j] = *(bf16x8*)&Bs[(w * 64 + j * 16 + lr) * 40 + kg * 8];
#pragma unroll
        for (int i = 0; i < 4; ++i)
#pragma unroll
            for (int j = 0; j < 4; ++j)
                acc[i][j] = __builtin_amdgcn_mfma_f32_16x16x32_bf16(a[i], b[j], acc[i][j], 0, 0, 0);
        __syncthreads();
    }
    double s = 0, s2 = 0;
#pragma unroll
    for (int i = 0; i < 4; ++i) {
        int rbase = m0 + i * 16 + kg * 4;
#pragma unroll
        for (int j = 0; j < 4; ++j) {
            int col = n0 + w * 64 + j * 16 + lr;
#pragma unroll
            for (int reg = 0; reg < 4; ++reg) {
                int row = rbase + reg;
                if (row < M) {
                    float v = acc[i][j][reg];
                    Cb[(size_t)row * N + col] = f2bf(v);
                    s += v;
                    s2 += (double)v * v;
                }
            }
        }
    }
    rs[tid] = s;
    rs2[tid] = s2;
    __syncthreads();
    for (int d = 128; d; d >>= 1) {
        if (tid < d) { rs[tid] += rs[tid + d]; rs2[tid] += rs2[tid + d]; }
        __syncthreads();
    }
    if (tid == 0) {
        int bid = blockIdx.y * gridDim.x + blockIdx.x;
        part[bid * 2] = rs[0];
        part[bid * 2 + 1] = rs2[0];
    }
}

// LN+ReLU, bf16 in-place, stats reduced inline from fp64 partials (one wave)
template <int C>
__global__ __launch_bounds__(256) void ln_relu_ip(unsigned short* __restrict__ z,
                                                  const float* __restrict__ w,
                                                  const float* __restrict__ b,
                                                  const double* __restrict__ part, int nb,
                                                  float invn, size_t n) {
    __shared__ float st[2];
    if (threadIdx.x < 64) {
        double s = 0, s2 = 0;
        for (int i = threadIdx.x; i < nb; i += 64) { s += part[2 * i]; s2 += part[2 * i + 1]; }
        for (int d = 32; d; d >>= 1) { s += __shfl_down(s, d); s2 += __shfl_down(s2, d); }
        if (threadIdx.x == 0) {
            float mu = (float)(s * invn);
            float var = (float)(s2 * invn) - mu * mu;
            st[0] = mu;
            st[1] = rsqrtf(var + 1e-5f);
        }
    }
    __syncthreads();
    float mu = st[0], inv = st[1];
    size_t stride = (size_t)gridDim.x * 256 * 4;
    for (size_t i = ((size_t)blockIdx.x * 256 + threadIdx.x) * 4; i < n; i += stride) {
        ushort4 v = *(const ushort4*)(z + i);
        int c = (int)(i & (C - 1));
        ushort4 o;
        o.x = f2bf(fmaxf((bf2f(v.x) - mu) * inv * w[c] + b[c], 0.f));
        o.y = f2bf(fmaxf((bf2f(v.y) - mu) * inv * w[c + 1] + b[c + 1], 0.f));
        o.z = f2bf(fmaxf((bf2f(v.z) - mu) * inv * w[c + 2] + b[c + 2], 0.f));
        o.w = f2bf(fmaxf((bf2f(v.w) - mu) * inv * w[c + 3] + b[c + 3], 0.f));
        *(ushort4*)(z + i) = o;
    }
}

// ---------------- fused LN2+ReLU+column-sum over raw z2 (bf16) ----------------
__global__ __launch_bounds__(256) void ln_colsum(const unsigned short* __restrict__ z2,
                                                 const float* __restrict__ w,
                                                 const float* __restrict__ b,
                                                 const double* __restrict__ part, int nb,
                                                 float invn, int n,
                                                 float* __restrict__ cspartT) {
    __shared__ float red[8 * 256];
    __shared__ float st[2];
    int tid = threadIdx.x;
    if (tid < 64) {
        double s = 0, s2 = 0;
        for (int i = tid; i < nb; i += 64) { s += part[2 * i]; s2 += part[2 * i + 1]; }
        for (int d = 32; d; d >>= 1) { s += __shfl_down(s, d); s2 += __shfl_down(s2, d); }
        if (tid == 0) {
            float mu = (float)(s * invn);
            float var = (float)(s2 * invn) - mu * mu;
            st[0] = mu;
            st[1] = rsqrtf(var + 1e-5f);
        }
    }
    __syncthreads();
    float mu = st[0], inv = st[1];
    int cg = tid & 31;
    int rl = tid >> 5;
    int c8 = cg * 8;
    float lw[8], lb[8];
#pragma unroll
    for (int i = 0; i < 8; ++i) { lw[i] = w[c8 + i] * inv; lb[i] = b[c8 + i] - mu * inv * w[c8 + i]; }
    int rows_per = (n + gridDim.x - 1) / gridDim.x;
    int r0 = blockIdx.x * rows_per;
    int r1 = min(n, r0 + rows_per);
    float acc[8] = {};
    for (int r = r0 + rl; r < r1; r += 8) {
        ushort8_t u = *(const ushort8_t*)(z2 + (size_t)r * 256 + c8);
#pragma unroll
        for (int i = 0; i < 8; ++i) acc[i] += fmaxf(bf2f(u[i]) * lw[i] + lb[i], 0.f);
    }
#pragma unroll
    for (int i = 0; i < 8; ++i) red[rl * 256 + c8 + i] = acc[i];
    __syncthreads();
    float s = 0;
#pragma unroll
    for (int r = 0; r < 8; ++r) s += red[r * 256 + tid];
    cspartT[tid * 64 + blockIdx.x] = s;
}

// ---------------- z, q, v  (single block, float4 split-K GEMVs) ----------------
__global__ __launch_bounds__(256) void zqv_kernel(const float* __restrict__ cspartT,
                                                  const float* __restrict__ mp_lin,
                                                  const float* __restrict__ fxg_w,
                                                  const float* __restrict__ fxg_b,
                                                  const float* __restrict__ fk_w,
                                                  const float* __restrict__ fk_b,
                                                  const float* __restrict__ fv_w,
                                                  const float* __restrict__ fv_b,
                                                  float* __restrict__ qv) {
    __shared__ float zp_s[256], u_s[128], z_s[256], ql_s[64];
    __shared__ float part_s[1024];
    int tid = threadIdx.x;
    {
        float s = 0;
        const float* p = cspartT + tid * 64;
#pragma unroll
        for (int i = 0; i < 16; ++i) {
            float4 v = *(const float4*)(p + i * 4);
            s += v.x + v.y + v.z + v.w;
        }
        zp_s[tid] = s;
    }
    __syncthreads();
    {
        int og = tid & 31, kc = tid >> 5;
        int j4 = og * 4;
        f32x4 a = {0.f, 0.f, 0.f, 0.f};
        for (int ci = 0; ci < 32; ++ci) {
            int c = kc * 32 + ci;
            float4 w = *(const float4*)(mp_lin + (size_t)c * 128 + j4);
            float zc = zp_s[c];
            a[0] += zc * w.x; a[1] += zc * w.y; a[2] += zc * w.z; a[3] += zc * w.w;
        }
#pragma unroll
        for (int i = 0; i < 4; ++i) part_s[kc * 128 + j4 + i] = a[i];
    }
    __syncthreads();
    if (tid < 128) {
        float s = 0;
#pragma unroll
        for (int kc = 0; kc < 8; ++kc) s += part_s[kc * 128 + tid];
        u_s[tid] = s;
    }
    __syncthreads();
    {
        int og = tid & 63, kc = tid >> 6;
        int j4 = og * 4;
        f32x4 a = {0.f, 0.f, 0.f, 0.f};
        for (int ci = 0; ci < 32; ++ci) {
            int c = kc * 32 + ci;
            float4 w = *(const float4*)(fxg_w + (size_t)c * 256 + j4);
            float uc = u_s[c];
            a[0] += uc * w.x; a[1] += uc * w.y; a[2] += uc * w.z; a[3] += uc * w.w;
        }
#pragma unroll
        for (int i = 0; i < 4; ++i) part_s[kc * 256 + j4 + i] = a[i];
    }
    __syncthreads();
    {
        float s = fxg_b[tid];
#pragma unroll
        for (int kc = 0; kc < 4; ++kc) s += part_s[kc * 256 + tid];
        z_s[tid] = s;
    }
    __syncthreads();
    {
        int og = tid & 15, kc = tid >> 4;
        int j4 = og * 4;
        f32x4 a = {0.f, 0.f, 0.f, 0.f};
        for (int ci = 0; ci < 16; ++ci) {
            int c = kc * 16 + ci;
            float4 w = *(const float4*)(fk_w + (size_t)c * 64 + j4);
            float zc = z_s[c];
            a[0] += zc * w.x; a[1] += zc * w.y; a[2] += zc * w.z; a[3] += zc * w.w;
        }
#pragma unroll
        for (int i = 0; i < 4; ++i) part_s[kc * 64 + j4 + i] = a[i];
    }
    __syncthreads();
    if (tid < 64) {
        float s = fk_b[tid];
#pragma unroll
        for (int kc = 0; kc < 16; ++kc) s += part_s[kc * 64 + tid];
        ql_s[tid] = s;
    }
    __syncthreads();
    {
        int og = tid & 15, kc = tid >> 4;
        int j4 = og * 4;
        f32x4 a = {0.f, 0.f, 0.f, 0.f};
        for (int ci = 0; ci < 16; ++ci) {
            int c = kc * 16 + ci;
            float4 w = *(const float4*)(fv_w + (size_t)c * 64 + j4);
            float zc = z_s[c];
            a[0] += zc * w.x; a[1] += zc * w.y; a[2] += zc * w.z; a[3] += zc * w.w;
        }
#pragma unroll
        for (int i = 0; i < 4; ++i) part_s[kc * 64 + j4 + i] = a[i];
    }
    __syncthreads();
    if (tid < 64) {
        float mx = ql_s[tid];
        for (int d = 32; d; d >>= 1) mx = fmaxf(mx, __shfl_xor(mx, d));
        float e = __expf(ql_s[tid] - mx);
        float s = e;
        for (int d = 32; d; d >>= 1) s += __shfl_xor(s, d);
        qv[tid] = e / s;
        float vv = fv_b[tid];
#pragma unroll
        for (int kc = 0; kc < 16; ++kc) vv += part_s[kc * 64 + tid];
        qv[64 + tid] = vv;
    }
}

// ---------------- memory keys/values + q-dot logits ----------------
__global__ __launch_bounds__(256) void mem_kv_logit(const float* __restrict__ mem,
                                                    const float* __restrict__ mfk_w,
                                                    const float* __restrict__ mfk_b,
                                                    const float* __restrict__ mfv_w,
                                                    const float* __restrict__ mfv_b,
                                                    const float* __restrict__ qv,
                                                    float* __restrict__ logits,
                                                    float* __restrict__ vm) {
    __shared__ float rows[4][128];
    __shared__ float qs[64];
    int tid = threadIdx.x;
    int r0 = blockIdx.x * 4;
    if (tid < 64) qs[tid] = qv[tid];
    for (int i = tid; i < 512; i += 256) rows[i >> 7][i & 127] = mem[(size_t)r0 * 128 + i];
    __syncthreads();
    int lr = tid >> 6;
    int lane = tid & 63;
    const float* row = rows[lr];
    float kl = mfk_b[lane], vl = mfv_b[lane];
#pragma unroll 8
    for (int c = 0; c < 128; ++c) {
        float rv = row[c];
        kl += rv * mfk_w[c * 64 + lane];
        vl += rv * mfv_w[c * 64 + lane];
    }
    float mx = kl;
    for (int d = 32; d; d >>= 1) mx = fmaxf(mx, __shfl_xor(mx, d));
    float e = __expf(kl - mx);
    float s = e;
    for (int d = 32; d; d >>= 1) s += __shfl_xor(s, d);
    float kval = e / s;
    float wl = kval * qs[lane];
    for (int d = 32; d; d >>= 1) wl += __shfl_xor(wl, d);
    size_t gr = (size_t)(r0 + lr);
    if (lane == 0) logits[gr] = wl;
    vm[gr * 64 + lane] = vl;
}

// ---------------- attention partials: 16 blocks/head, 64 slots/block ----------------
__global__ __launch_bounds__(256) void attend_part(const float* __restrict__ logits,
                                                   const float* __restrict__ vm,
                                                   float* __restrict__ part) {
    int b = blockIdx.x;
    int h = b >> 4;
    int s0 = (b & 15) * 64;
    int tid = threadIdx.x;
    __shared__ float els[64];
    __shared__ float pr[4][64];
    __shared__ float lmax_s, lsum_s;
    if (tid < 64) {
        float lg = logits[h * 1024 + s0 + tid];
        float m = lg;
        for (int d = 32; d; d >>= 1) m = fmaxf(m, __shfl_xor(m, d));
        float e = __expf(lg - m);
        els[tid] = e;
        float s = e;
        for (int d = 32; d; d >>= 1) s += __shfl_xor(s, d);
        if (tid == 0) { lmax_s = m; lsum_s = s; }
    }
    __syncthreads();
    int dd = tid & 63, g = tid >> 6;
    float acc = 0;
    for (int s = g; s < 64; s += 4)
        acc += els[s] * vm[((size_t)h * 1024 + s0 + s) * 64 + dd];
    pr[g][dd] = acc;
    __syncthreads();
    if (tid < 64) {
        float pv = pr[0][tid] + pr[1][tid] + pr[2][tid] + pr[3][tid];
        part[b * 66 + 2 + tid] = pv;
        if (tid == 0) { part[b * 66] = lmax_s; part[b * 66 + 1] = lsum_s; }
    }
}

// ---------------- final merge + m_out GEMV (float4 split-K) ----------------
__global__ __launch_bounds__(256) void attend_final(const float* __restrict__ part,
                                                    const float* __restrict__ mfx_w,
                                                    const float* __restrict__ mfx_b,
                                                    float* __restrict__ m_out) {
    __shared__ float mv[256];
    __shared__ float part_s[1024];
    int tid = threadIdx.x;
    int h = tid >> 6, dd = tid & 63;
    float gmax = -1e30f;
#pragma unroll
    for (int p = 0; p < 16; ++p) gmax = fmaxf(gmax, part[(h * 16 + p) * 66]);
    float total = 0.f, acc = 0.f;
#pragma unroll
    for (int p = 0; p < 16; ++p) {
        float sc = __expf(part[(h * 16 + p) * 66] - gmax);
        total += part[(h * 16 + p) * 66 + 1] * sc;
        acc += part[(h * 16 + p) * 66 + 2 + dd] * sc;
    }
    mv[h * 64 + dd] = acc / total;
    __syncthreads();
    {
        int og = tid & 15, kc = tid >> 4;
        int j4 = og * 4;
        f32x4 a = {0.f, 0.f, 0.f, 0.f};
        for (int ci = 0; ci < 16; ++ci) {
            int c = kc * 16 + ci;
            float4 w = *(const float4*)(mfx_w + (size_t)c * 64 + j4);
            float mc = mv[c];
            a[0] += mc * w.x; a[1] += mc * w.y; a[2] += mc * w.z; a[3] += mc * w.w;
        }
#pragma unroll
        for (int i = 0; i < 4; ++i) part_s[kc * 64 + j4 + i] = a[i];
    }
    __syncthreads();
    if (tid < 64) {
        float s = mfx_b[tid];
#pragma unroll
        for (int kc = 0; kc < 16; ++kc) s += part_s[kc * 64 + tid];
        m_out[tid] = s;
    }
}

// ---------------- final MLP head, one block per type row ----------------
__device__ __forceinline__ float block_sum_256(float v, float* red) {
    int tid = threadIdx.x;
    red[tid] = v;
    __syncthreads();
    for (int d = 128; d; d >>= 1) { if (tid < d) red[tid] += red[tid + d]; __syncthreads(); }
    float r = red[0];
    __syncthreads();
    return r;
}

__global__ __launch_bounds__(256) void head_kernel(
    const float* __restrict__ x, const int* __restrict__ index_p,
    const int* __restrict__ inp_types, const float* __restrict__ log_return,
    const float* __restrict__ emb, const float* __restrict__ qv,
    const float* __restrict__ m_out, const float* __restrict__ f1_w,
    const float* __restrict__ n1_w, const float* __restrict__ n1_b,
    const float* __restrict__ f2_w, const float* __restrict__ n2_w,
    const float* __restrict__ n2_b, const float* __restrict__ f3_w,
    const float* __restrict__ f3_b, float* __restrict__ out) {
    __shared__ float feat[273];
    __shared__ float h1[512];
    __shared__ float h2[256];
    __shared__ float red[256];
    __shared__ float l3[3];
    int r = blockIdx.x, tid = threadIdx.x;
    int idx = index_p[0];
    for (int i = tid; i < 273; i += 256) {
        float val;
        if (i < 128) val = x[(size_t)idx * 128 + i];
        else if (i < 144) val = emb[inp_types[r] * 16 + (i - 128)];
        else if (i == 144) val = log_return[r];
        else if (i < 209) val = qv[64 + (i - 145)];
        else val = m_out[i - 209];
        feat[i] = val;
    }
    __syncthreads();
    float a0 = 0, a1 = 0;
    for (int c = 0; c < 273; ++c) {
        float f = feat[c];
        a0 += f * f1_w[c * 512 + tid];
        a1 += f * f1_w[c * 512 + tid + 256];
    }
    float mu = block_sum_256(a0 + a1, red) / 512.f;
    float c0 = a0 - mu, c1 = a1 - mu;
    float var = block_sum_256(c0 * c0 + c1 * c1, red) / 512.f;
    float inv = rsqrtf(var + 1e-5f);
    h1[tid] = fmaxf(c0 * inv * n1_w[tid] + n1_b[tid], 0.f);
    h1[tid + 256] = fmaxf(c1 * inv * n1_w[tid + 256] + n1_b[tid + 256], 0.f);
    __syncthreads();
    float b0 = 0;
    for (int c = 0; c < 512; ++c) b0 += h1[c] * f2_w[c * 256 + tid];
    float mu2 = block_sum_256(b0, red) / 256.f;
    float cc = b0 - mu2;
    float var2 = block_sum_256(cc * cc, red) / 256.f;
    float inv2 = rsqrtf(var2 + 1e-5f);
    h2[tid] = fmaxf(cc * inv2 * n2_w[tid] + n2_b[tid], 0.f);
    __syncthreads();
    if (tid < 3) {
        float a = f3_b[tid];
        for (int c = 0; c < 256; ++c) a += h2[c] * f3_w[c * 3 + tid];
        l3[tid] = a;
    }
    __syncthreads();
    if (tid < 3) {
        float mx = fmaxf(l3[0], fmaxf(l3[1], l3[2]));
        float s = __expf(l3[0] - mx) + __expf(l3[1] - mx) + __expf(l3[2] - mx);
        out[r * 3 + tid] = __expf(l3[tid] - mx) / s;
    }
}

extern "C" void kernel_launch(void* const* d_in, const int* in_sizes, int n_in,
                              void* d_out, int out_size, void* d_ws, size_t ws_size,
                              hipStream_t stream) {
    const float* x = (const float*)d_in[0];
    const int* ei = (const int*)d_in[1];
    const int* index_p = (const int*)d_in[2];
    const int* inp_types = (const int*)d_in[3];
    const float* log_return = (const float*)d_in[4];
    const float* t1 = (const float*)d_in[5];
    const float* W1l = (const float*)d_in[6];
    const float* W1r = (const float*)d_in[7];
    const float* ln1g_w = (const float*)d_in[8];
    const float* ln1g_b = (const float*)d_in[9];
    const float* t2 = (const float*)d_in[10];
    const float* W2l = (const float*)d_in[11];
    const float* W2r = (const float*)d_in[12];
    const float* ln2g_w = (const float*)d_in[13];
    const float* ln2g_b = (const float*)d_in[14];
    // d_in[15] mp_k, d_in[16] mp_conv: provably unused (K=1 makes S==1)
    const float* mp_lin = (const float*)d_in[17];
    const float* fxg_w = (const float*)d_in[18];
    const float* fxg_b = (const float*)d_in[19];
    const float* emb = (const float*)d_in[20];
    const float* fk_w = (const float*)d_in[21];
    const float* fk_b = (const float*)d_in[22];
    const float* fv_w = (const float*)d_in[23];
    const float* fv_b = (const float*)d_in[24];
    const float* mem = (const float*)d_in[25];
    const float* mfk_w = (const float*)d_in[26];
    const float* mfk_b = (const float*)d_in[27];
    const float* mfv_w = (const float*)d_in[28];
    const float* mfv_b = (const float*)d_in[29];
    const float* mfx_w = (const float*)d_in[30];
    const float* mfx_b = (const float*)d_in[31];
    const float* f1_w = (const float*)d_in[32];
    const float* n1_w = (const float*)d_in[33];
    const float* n1_b = (const float*)d_in[34];
    const float* f2_w = (const float*)d_in[35];
    const float* n2_w = (const float*)d_in[36];
    const float* n2_b = (const float*)d_in[37];
    const float* f3_w = (const float*)d_in[38];
    const float* f3_b = (const float*)d_in[39];
    float* out = (float*)d_out;

    int n = in_sizes[0] / 128;
    int E = in_sizes[1] / 2;
    int T = in_sizes[3];
    const int* src = ei;
    const int* dst = ei + E;

    char* w = (char*)d_ws;
    auto alloc = [&](size_t bytes) {
        char* p = w;
        w += (bytes + 255) & ~(size_t)255;
        return p;
    };
    int* counts = (int*)alloc((size_t)n * 4);
    int* off = (int*)alloc((size_t)(n + 1) * 4);
    int* srcs = (int*)alloc((size_t)E * 4);
    unsigned short* xb = (unsigned short*)alloc((size_t)n * 128 * 2);
    unsigned short* agg1b = (unsigned short*)alloc((size_t)n * 128 * 2);
    unsigned short* z1b = (unsigned short*)alloc((size_t)n * 512 * 2);
    unsigned short* agg2b = (unsigned short*)alloc((size_t)n * 512 * 2);
    unsigned short* z2b = (unsigned short*)alloc((size_t)n * 256 * 2);
    double* partd = (double*)alloc(2048 * 2 * 8);
    float* cspartT = (float*)alloc(256 * 64 * 4);
    float* qv = (float*)alloc(128 * 4);
    float* logits = (float*)alloc((size_t)4 * 1024 * 4);
    float* vm = (float*)alloc((size_t)4 * 1024 * 64 * 4);
    float* apart = (float*)alloc(64 * 66 * 4);
    float* m_out = (float*)alloc(64 * 4);
    unsigned short* Bt1 = (unsigned short*)alloc((size_t)512 * 256 * 2);
    unsigned short* Bt2 = (unsigned short*)alloc((size_t)256 * 1024 * 2);

    int nblk_e = (E + 255) / 256;
    int mblk64 = (n + 63) / 64;

    // CSR build + fused prologue (count/cast/pack are independent)
    hipMemsetAsync(counts, 0, (size_t)n * 4, stream);
    prep_kernel<<<nblk_e, 256, 0, stream>>>(dst, E, counts, x, xb, (size_t)n * 128 / 4,
                                            W1l, W1r, Bt1, W2l, W2r, Bt2);
    scan_kernel<20><<<1, 1024, 0, stream>>>(counts, off, n);  // also zeroes counts
    fill_kernel<<<nblk_e, 256, 0, stream>>>(src, dst, E, off, counts, srcs);

    // SAGE layer 1: z1 = agg1@W1l + x@W1r  (fused MFMA GEMM + stats)
    agg128<<<(n + 3) / 4, 256, 0, stream>>>(xb, t1, off, srcs, agg1b, n);
    gemm_dual_mfma3<<<dim3(2, mblk64), 256, 0, stream>>>(agg1b, xb, Bt1, z1b, partd, n, 512, 128, 128);
    ln_relu_ip<512><<<1024, 256, 0, stream>>>(z1b, ln1g_w, ln1g_b, partd, 2 * mblk64,
                                              1.0f / ((float)n * 512.f), (size_t)n * 512);

    // SAGE layer 2: z2 = agg2@W2l + z1@W2r
    agg512<<<(n + 3) / 4, 256, 0, stream>>>(z1b, t2, off, srcs, agg2b, n);
    gemm_dual_mfma3<<<dim3(1, mblk64), 256, 0, stream>>>(agg2b, z1b, Bt2, z2b, partd, n, 256, 512, 512);

    // LN2+ReLU fused into MemPooling column sum (z2 post-LN has no other consumer)
    ln_colsum<<<64, 256, 0, stream>>>(z2b, ln2g_w, ln2g_b, partd, mblk64,
                                      1.0f / ((float)n * 256.f), n, cspartT);
    zqv_kernel<<<1, 256, 0, stream>>>(cspartT, mp_lin, fxg_w, fxg_b, fk_w, fk_b, fv_w, fv_b, qv);

    // MultiHeadMemory (parallel softmax-attention)
    mem_kv_logit<<<1024, 256, 0, stream>>>(mem, mfk_w, mfk_b, mfv_w, mfv_b, qv, logits, vm);
    attend_part<<<64, 256, 0, stream>>>(logits, vm, apart);
    attend_final<<<1, 256, 0, stream>>>(apart, mfx_w, mfx_b, m_out);

    // head
    head_kernel<<<T, 256, 0, stream>>>(x, index_p, inp_types, log_return, emb, qv, m_out,
                                       f1_w, n1_w, n1_b, f2_w, n2_w, n2_b, f3_w, f3_b, out);
}

// Round 12
// 287.061 us; speedup vs baseline: 1.0119x; 1.0119x over previous
//
#include <hip/hip_runtime.h>

typedef __attribute__((ext_vector_type(8))) short bf16x8;
typedef __attribute__((ext_vector_type(8))) unsigned short ushort8_t;
typedef __attribute__((ext_vector_type(4))) float f32x4;

__device__ __forceinline__ unsigned short f2bf(float f) {
    unsigned int x = __float_as_uint(f);
    unsigned int r = x + 0x7fffu + ((x >> 16) & 1u);
    return (unsigned short)(r >> 16);
}
__device__ __forceinline__ float bf2f(unsigned short u) {
    return __uint_as_float(((unsigned int)u) << 16);
}
// raw v_exp_f32 — no libm denormal fixup (precise exp2f cost r7/r8 ~17us in agg512)
__device__ __forceinline__ float fexp2(float x) { return __builtin_amdgcn_exp2f(x); }

#define LOG2E 1.44269504089f

// ---------------- fused prologue: edge-count + x cast + both weight packs ----------------
__global__ __launch_bounds__(256) void prep_kernel(
    const int* __restrict__ dst, int E, int* __restrict__ counts,
    const float* __restrict__ x, unsigned short* __restrict__ xb, size_t nx4,
    const float* __restrict__ W1l, const float* __restrict__ W1r, unsigned short* __restrict__ Bt1,
    const float* __restrict__ W2l, const float* __restrict__ W2r, unsigned short* __restrict__ Bt2) {
    int i = blockIdx.x * 256 + threadIdx.x;
    int total = gridDim.x * 256;
    if (i < E) atomicAdd(&counts[dst[i]], 1);
    for (size_t j = i; j < nx4; j += total) {
        float4 v = *(const float4*)(x + j * 4);
        ushort4 o;
        o.x = f2bf(v.x); o.y = f2bf(v.y); o.z = f2bf(v.z); o.w = f2bf(v.w);
        *(ushort4*)(xb + j * 4) = o;
    }
    if (i < 512 * 256) {
        int nn = i >> 8, k = i & 255;
        float v = (k < 128) ? W1l[(size_t)k * 512 + nn] : W1r[(size_t)(k - 128) * 512 + nn];
        Bt1[i] = f2bf(v);
    }
    if (i < 256 * 1024) {
        int nn = i >> 10, k = i & 1023;
        float v = (k < 512) ? W2l[(size_t)k * 256 + nn] : W2r[(size_t)(k - 512) * 256 + nn];
        Bt2[i] = f2bf(v);
    }
}

// also zeroes cnt after reading (cursor reuse, saves a memset dispatch)
template <int CHUNK>
__global__ __launch_bounds__(1024) void scan_kernel(int* __restrict__ cnt,
                                                    int* __restrict__ off, int n) {
    __shared__ int s[1024];
    int tid = threadIdx.x;
    int base = tid * CHUNK;
    int loc[CHUNK];
    int sum = 0;
#pragma unroll
    for (int i = 0; i < CHUNK; ++i) {
        int idx = base + i;
        int v = 0;
        if (idx < n) { v = cnt[idx]; cnt[idx] = 0; }
        sum += v;
        loc[i] = sum;
    }
    s[tid] = sum;
    __syncthreads();
    for (int d = 1; d < 1024; d <<= 1) {
        int t = (tid >= d) ? s[tid - d] : 0;
        __syncthreads();
        s[tid] += t;
        __syncthreads();
    }
    int prev = (tid > 0) ? s[tid - 1] : 0;
    if (tid == 0) off[0] = 0;
#pragma unroll
    for (int i = 0; i < CHUNK; ++i) {
        int idx = base + i;
        if (idx < n) off[idx + 1] = prev + loc[i];
    }
}

__global__ void fill_kernel(const int* __restrict__ src, const int* __restrict__ dst, int E,
                            const int* __restrict__ off, int* __restrict__ cursor,
                            int* __restrict__ srcs) {
    int i = blockIdx.x * 256 + threadIdx.x;
    if (i < E) {
        int d = dst[i];
        int p = atomicAdd(&cursor[d], 1);
        srcs[off[d] + p] = src[i];
    }
}

// ---------------- softmax aggregation C=512, channel-split (grid.y=2) ----------------
// Each half processes 256 channels (4 ch/lane, ushort4): halves the per-XCD gather
// working set (10MB slice) to cut the 6.6x L2-miss re-fetch seen at r11 (FETCH=133MB
// vs 20MB table). srcs read twice (L2-cached, 1.3MB).
__global__ __launch_bounds__(256) void agg512s(const unsigned short* __restrict__ h,
                                               const float* __restrict__ t,
                                               const int* __restrict__ off,
                                               const int* __restrict__ srcs,
                                               unsigned short* __restrict__ agg, int n) {
    int wid = threadIdx.x >> 6, lane = threadIdx.x & 63;
    int node = blockIdx.x * 4 + wid;
    if (node >= n) return;
    int beg = off[node], end = off[node + 1];
    int col = blockIdx.y * 256 + lane * 4;
    float tc0 = t[col] * LOG2E, tc1 = t[col + 1] * LOG2E;
    float tc2 = t[col + 2] * LOG2E, tc3 = t[col + 3] * LOG2E;
    float sE0 = 0.f, sE1 = 0.f, sE2 = 0.f, sE3 = 0.f;
    float sW0 = 0.f, sW1 = 0.f, sW2 = 0.f, sW3 = 0.f;
#define P4(u)                                                        \
    {                                                                \
        float v0 = bf2f(u.x), v1 = bf2f(u.y);                        \
        float v2 = bf2f(u.z), v3 = bf2f(u.w);                        \
        float w0_ = fexp2(v0 * tc0), w1_ = fexp2(v1 * tc1);          \
        float w2_ = fexp2(v2 * tc2), w3_ = fexp2(v3 * tc3);          \
        sE0 += w0_; sW0 += v0 * w0_; sE1 += w1_; sW1 += v1 * w1_;    \
        sE2 += w2_; sW2 += v2 * w2_; sE3 += w3_; sW3 += v3 * w3_;    \
    }
    int e = beg;
    for (; e + 4 <= end; e += 4) {
        ushort4 u0 = *(const ushort4*)(h + (size_t)srcs[e] * 512 + col);
        ushort4 u1 = *(const ushort4*)(h + (size_t)srcs[e + 1] * 512 + col);
        ushort4 u2 = *(const ushort4*)(h + (size_t)srcs[e + 2] * 512 + col);
        ushort4 u3 = *(const ushort4*)(h + (size_t)srcs[e + 3] * 512 + col);
        P4(u0) P4(u1) P4(u2) P4(u3)
    }
    for (; e < end; ++e) {
        ushort4 u0 = *(const ushort4*)(h + (size_t)srcs[e] * 512 + col);
        P4(u0)
    }
#undef P4
    ushort4 o;
    o.x = f2bf((end > beg) ? (sW0 / sE0) : 0.f);
    o.y = f2bf((end > beg) ? (sW1 / sE1) : 0.f);
    o.z = f2bf((end > beg) ? (sW2 / sE2) : 0.f);
    o.w = f2bf((end > beg) ? (sW3 / sE3) : 0.f);
    *(ushort4*)(agg + (size_t)node * 512 + col) = o;
}

// ---------------- softmax aggregation, wave-per-node, C=128 (2 ch/lane) ----------------
__global__ __launch_bounds__(256) void agg128(const unsigned short* __restrict__ h,
                                              const float* __restrict__ t,
                                              const int* __restrict__ off,
                                              const int* __restrict__ srcs,
                                              unsigned short* __restrict__ agg, int n) {
    int wid = threadIdx.x >> 6, lane = threadIdx.x & 63;
    int node = blockIdx.x * 4 + wid;
    if (node >= n) return;
    int beg = off[node], end = off[node + 1];
    int col = lane * 2;
    float t0 = t[col] * LOG2E, t1 = t[col + 1] * LOG2E;
    float e0 = 0.f, e1 = 0.f, w0 = 0.f, w1 = 0.f;
#define P2(u)                                          \
    {                                                  \
        float a = bf2f(u.x), b = bf2f(u.y);            \
        float xa = fexp2(a * t0), xb = fexp2(b * t1);  \
        e0 += xa; e1 += xb; w0 += a * xa; w1 += b * xb; \
    }
    int e = beg;
    for (; e + 4 <= end; e += 4) {
        ushort2 u0 = *(const ushort2*)(h + (size_t)srcs[e] * 128 + col);
        ushort2 u1 = *(const ushort2*)(h + (size_t)srcs[e + 1] * 128 + col);
        ushort2 u2 = *(const ushort2*)(h + (size_t)srcs[e + 2] * 128 + col);
        ushort2 u3 = *(const ushort2*)(h + (size_t)srcs[e + 3] * 128 + col);
        P2(u0) P2(u1) P2(u2) P2(u3)
    }
    for (; e < end; ++e) {
        ushort2 u0 = *(const ushort2*)(h + (size_t)srcs[e] * 128 + col);
        P2(u0)
    }
#undef P2
    ushort2 o;
    o.x = f2bf((end > beg) ? (w0 / e0) : 0.f);
    o.y = f2bf((end > beg) ? (w1 / e1) : 0.f);
    *(ushort2*)(agg + (size_t)node * 128 + col) = o;
}

// ---------------- fused dual bf16 MFMA GEMM + fp64 stats partials ----------------
// 64x256 tile, 256 threads (4 waves = 4 column quadrants). reg-staged, pad-40 LDS.
__global__ __launch_bounds__(256) void gemm_dual_mfma3(
    const unsigned short* __restrict__ A1, const unsigned short* __restrict__ A2,
    const unsigned short* __restrict__ Bt,
    unsigned short* __restrict__ Cb, double* __restrict__ part,
    int M, int N, int K1, int K2) {
    const int Kc = K1 + K2;
    __shared__ unsigned short As[64 * 40];
    __shared__ unsigned short Bs[256 * 40];
    __shared__ double rs[256], rs2[256];
    int tid = threadIdx.x;
    int lane = tid & 63, w = tid >> 6;  // w = column quadrant
    int m0 = blockIdx.y * 64, n0 = blockIdx.x * 256;
    f32x4 acc[4][4] = {};
    int kg = lane >> 4, lr = lane & 15;

    for (int k0 = 0; k0 < Kc; k0 += 32) {
        const unsigned short* Asrc;
        int kk, Ksrc;
        if (k0 < K1) { Asrc = A1; kk = k0; Ksrc = K1; }
        else         { Asrc = A2; kk = k0 - K1; Ksrc = K2; }
        {
            int r = tid >> 2, ch = tid & 3;
            int gr = m0 + r;
            ushort8_t v = {0, 0, 0, 0, 0, 0, 0, 0};
            if (gr < M) v = *(const ushort8_t*)(Asrc + (size_t)gr * Ksrc + kk + ch * 8);
            *(ushort8_t*)&As[r * 40 + ch * 8] = v;
        }
#pragma unroll
        for (int it = 0; it < 4; ++it) {
            int idx = tid + it * 256;
            int r = idx >> 2, ch = idx & 3;
            const unsigned short* srcp = Bt + (size_t)(n0 + r) * Kc + k0 + ch * 8;
            *(ushort8_t*)&Bs[r * 40 + ch * 8] = *(const ushort8_t*)srcp;
        }
        __syncthreads();
        bf16x8 a[4], b[4];
#pragma unroll
        for (int i = 0; i < 4; ++i)
            a[i] = *(bf16x8*)&As[(i * 16 + lr) * 40 + kg * 8];
#pragma unroll
        for (int j = 0; j < 4; ++j)
            b[j] = *(bf16x8*)&Bs[(w * 64 + j * 16 + lr) * 40 + kg * 8];
#pragma unroll
        for (int i = 0; i < 4; ++i)
#pragma unroll
            for (int j = 0; j < 4; ++j)
                acc[i][j] = __builtin_amdgcn_mfma_f32_16x16x32_bf16(a[i], b[j], acc[i][j], 0, 0, 0);
        __syncthreads();
    }
    double s = 0, s2 = 0;
#pragma unroll
    for (int i = 0; i < 4; ++i) {
        int rbase = m0 + i * 16 + kg * 4;
#pragma unroll
        for (int j = 0; j < 4; ++j) {
            int col = n0 + w * 64 + j * 16 + lr;
#pragma unroll
            for (int reg = 0; reg < 4; ++reg) {
                int row = rbase + reg;
                if (row < M) {
                    float v = acc[i][j][reg];
                    Cb[(size_t)row * N + col] = f2bf(v);
                    s += v;
                    s2 += (double)v * v;
                }
            }
        }
    }
    rs[tid] = s;
    rs2[tid] = s2;
    __syncthreads();
    for (int d = 128; d; d >>= 1) {
        if (tid < d) { rs[tid] += rs[tid + d]; rs2[tid] += rs2[tid + d]; }
        __syncthreads();
    }
    if (tid == 0) {
        int bid = blockIdx.y * gridDim.x + blockIdx.x;
        part[bid * 2] = rs[0];
        part[bid * 2 + 1] = rs2[0];
    }
}

// LN+ReLU, bf16 in-place, stats reduced inline from fp64 partials (one wave)
template <int C>
__global__ __launch_bounds__(256) void ln_relu_ip(unsigned short* __restrict__ z,
                                                  const float* __restrict__ w,
                                                  const float* __restrict__ b,
                                                  const double* __restrict__ part, int nb,
                                                  float invn, size_t n) {
    __shared__ float st[2];
    if (threadIdx.x < 64) {
        double s = 0, s2 = 0;
        for (int i = threadIdx.x; i < nb; i += 64) { s += part[2 * i]; s2 += part[2 * i + 1]; }
        for (int d = 32; d; d >>= 1) { s += __shfl_down(s, d); s2 += __shfl_down(s2, d); }
        if (threadIdx.x == 0) {
            float mu = (float)(s * invn);
            float var = (float)(s2 * invn) - mu * mu;
            st[0] = mu;
            st[1] = rsqrtf(var + 1e-5f);
        }
    }
    __syncthreads();
    float mu = st[0], inv = st[1];
    size_t stride = (size_t)gridDim.x * 256 * 4;
    for (size_t i = ((size_t)blockIdx.x * 256 + threadIdx.x) * 4; i < n; i += stride) {
        ushort4 v = *(const ushort4*)(z + i);
        int c = (int)(i & (C - 1));
        ushort4 o;
        o.x = f2bf(fmaxf((bf2f(v.x) - mu) * inv * w[c] + b[c], 0.f));
        o.y = f2bf(fmaxf((bf2f(v.y) - mu) * inv * w[c + 1] + b[c + 1], 0.f));
        o.z = f2bf(fmaxf((bf2f(v.z) - mu) * inv * w[c + 2] + b[c + 2], 0.f));
        o.w = f2bf(fmaxf((bf2f(v.w) - mu) * inv * w[c + 3] + b[c + 3], 0.f));
        *(ushort4*)(z + i) = o;
    }
}

// ---------------- fused LN2+ReLU+column-sum over raw z2 (bf16) ----------------
__global__ __launch_bounds__(256) void ln_colsum(const unsigned short* __restrict__ z2,
                                                 const float* __restrict__ w,
                                                 const float* __restrict__ b,
                                                 const double* __restrict__ part, int nb,
                                                 float invn, int n,
                                                 float* __restrict__ cspartT) {
    __shared__ float red[8 * 256];
    __shared__ float st[2];
    int tid = threadIdx.x;
    if (tid < 64) {
        double s = 0, s2 = 0;
        for (int i = tid; i < nb; i += 64) { s += part[2 * i]; s2 += part[2 * i + 1]; }
        for (int d = 32; d; d >>= 1) { s += __shfl_down(s, d); s2 += __shfl_down(s2, d); }
        if (tid == 0) {
            float mu = (float)(s * invn);
            float var = (float)(s2 * invn) - mu * mu;
            st[0] = mu;
            st[1] = rsqrtf(var + 1e-5f);
        }
    }
    __syncthreads();
    float mu = st[0], inv = st[1];
    int cg = tid & 31;
    int rl = tid >> 5;
    int c8 = cg * 8;
    float lw[8], lb[8];
#pragma unroll
    for (int i = 0; i < 8; ++i) { lw[i] = w[c8 + i] * inv; lb[i] = b[c8 + i] - mu * inv * w[c8 + i]; }
    int rows_per = (n + gridDim.x - 1) / gridDim.x;
    int r0 = blockIdx.x * rows_per;
    int r1 = min(n, r0 + rows_per);
    float acc[8] = {};
    for (int r = r0 + rl; r < r1; r += 8) {
        ushort8_t u = *(const ushort8_t*)(z2 + (size_t)r * 256 + c8);
#pragma unroll
        for (int i = 0; i < 8; ++i) acc[i] += fmaxf(bf2f(u[i]) * lw[i] + lb[i], 0.f);
    }
#pragma unroll
    for (int i = 0; i < 8; ++i) red[rl * 256 + c8 + i] = acc[i];
    __syncthreads();
    float s = 0;
#pragma unroll
    for (int r = 0; r < 8; ++r) s += red[r * 256 + tid];
    cspartT[tid * 64 + blockIdx.x] = s;
}

// ---------------- z, q, v  (single block, float4 split-K GEMVs) ----------------
__global__ __launch_bounds__(256) void zqv_kernel(const float* __restrict__ cspartT,
                                                  const float* __restrict__ mp_lin,
                                                  const float* __restrict__ fxg_w,
                                                  const float* __restrict__ fxg_b,
                                                  const float* __restrict__ fk_w,
                                                  const float* __restrict__ fk_b,
                                                  const float* __restrict__ fv_w,
                                                  const float* __restrict__ fv_b,
                                                  float* __restrict__ qv) {
    __shared__ float zp_s[256], u_s[128], z_s[256], ql_s[64];
    __shared__ float part_s[1024];
    int tid = threadIdx.x;
    {
        float s = 0;
        const float* p = cspartT + tid * 64;
#pragma unroll
        for (int i = 0; i < 16; ++i) {
            float4 v = *(const float4*)(p + i * 4);
            s += v.x + v.y + v.z + v.w;
        }
        zp_s[tid] = s;
    }
    __syncthreads();
    {
        int og = tid & 31, kc = tid >> 5;
        int j4 = og * 4;
        f32x4 a = {0.f, 0.f, 0.f, 0.f};
        for (int ci = 0; ci < 32; ++ci) {
            int c = kc * 32 + ci;
            float4 w = *(const float4*)(mp_lin + (size_t)c * 128 + j4);
            float zc = zp_s[c];
            a[0] += zc * w.x; a[1] += zc * w.y; a[2] += zc * w.z; a[3] += zc * w.w;
        }
#pragma unroll
        for (int i = 0; i < 4; ++i) part_s[kc * 128 + j4 + i] = a[i];
    }
    __syncthreads();
    if (tid < 128) {
        float s = 0;
#pragma unroll
        for (int kc = 0; kc < 8; ++kc) s += part_s[kc * 128 + tid];
        u_s[tid] = s;
    }
    __syncthreads();
    {
        int og = tid & 63, kc = tid >> 6;
        int j4 = og * 4;
        f32x4 a = {0.f, 0.f, 0.f, 0.f};
        for (int ci = 0; ci < 32; ++ci) {
            int c = kc * 32 + ci;
            float4 w = *(const float4*)(fxg_w + (size_t)c * 256 + j4);
            float uc = u_s[c];
            a[0] += uc * w.x; a[1] += uc * w.y; a[2] += uc * w.z; a[3] += uc * w.w;
        }
#pragma unroll
        for (int i = 0; i < 4; ++i) part_s[kc * 256 + j4 + i] = a[i];
    }
    __syncthreads();
    {
        float s = fxg_b[tid];
#pragma unroll
        for (int kc = 0; kc < 4; ++kc) s += part_s[kc * 256 + tid];
        z_s[tid] = s;
    }
    __syncthreads();
    {
        int og = tid & 15, kc = tid >> 4;
        int j4 = og * 4;
        f32x4 a = {0.f, 0.f, 0.f, 0.f};
        for (int ci = 0; ci < 16; ++ci) {
            int c = kc * 16 + ci;
            float4 w = *(const float4*)(fk_w + (size_t)c * 64 + j4);
            float zc = z_s[c];
            a[0] += zc * w.x; a[1] += zc * w.y; a[2] += zc * w.z; a[3] += zc * w.w;
        }
#pragma unroll
        for (int i = 0; i < 4; ++i) part_s[kc * 64 + j4 + i] = a[i];
    }
    __syncthreads();
    if (tid < 64) {
        float s = fk_b[tid];
#pragma unroll
        for (int kc = 0; kc < 16; ++kc) s += part_s[kc * 64 + tid];
        ql_s[tid] = s;
    }
    __syncthreads();
    {
        int og = tid & 15, kc = tid >> 4;
        int j4 = og * 4;
        f32x4 a = {0.f, 0.f, 0.f, 0.f};
        for (int ci = 0; ci < 16; ++ci) {
            int c = kc * 16 + ci;
            float4 w = *(const float4*)(fv_w + (size_t)c * 64 + j4);
            float zc = z_s[c];
            a[0] += zc * w.x; a[1] += zc * w.y; a[2] += zc * w.z; a[3] += zc * w.w;
        }
#pragma unroll
        for (int i = 0; i < 4; ++i) part_s[kc * 64 + j4 + i] = a[i];
    }
    __syncthreads();
    if (tid < 64) {
        float mx = ql_s[tid];
        for (int d = 32; d; d >>= 1) mx = fmaxf(mx, __shfl_xor(mx, d));
        float e = __expf(ql_s[tid] - mx);
        float s = e;
        for (int d = 32; d; d >>= 1) s += __shfl_xor(s, d);
        qv[tid] = e / s;
        float vv = fv_b[tid];
#pragma unroll
        for (int kc = 0; kc < 16; ++kc) vv += part_s[kc * 64 + tid];
        qv[64 + tid] = vv;
    }
}

// ---------------- memory keys/values + q-dot logits ----------------
__global__ __launch_bounds__(256) void mem_kv_logit(const float* __restrict__ mem,
                                                    const float* __restrict__ mfk_w,
                                                    const float* __restrict__ mfk_b,
                                                    const float* __restrict__ mfv_w,
                                                    const float* __restrict__ mfv_b,
                                                    const float* __restrict__ qv,
                                                    float* __restrict__ logits,
                                                    float* __restrict__ vm) {
    __shared__ float rows[4][128];
    __shared__ float qs[64];
    int tid = threadIdx.x;
    int r0 = blockIdx.x * 4;
    if (tid < 64) qs[tid] = qv[tid];
    for (int i = tid; i < 512; i += 256) rows[i >> 7][i & 127] = mem[(size_t)r0 * 128 + i];
    __syncthreads();
    int lr = tid >> 6;
    int lane = tid & 63;
    const float* row = rows[lr];
    float kl = mfk_b[lane], vl = mfv_b[lane];
#pragma unroll 8
    for (int c = 0; c < 128; ++c) {
        float rv = row[c];
        kl += rv * mfk_w[c * 64 + lane];
        vl += rv * mfv_w[c * 64 + lane];
    }
    float mx = kl;
    for (int d = 32; d; d >>= 1) mx = fmaxf(mx, __shfl_xor(mx, d));
    float e = __expf(kl - mx);
    float s = e;
    for (int d = 32; d; d >>= 1) s += __shfl_xor(s, d);
    float kval = e / s;
    float wl = kval * qs[lane];
    for (int d = 32; d; d >>= 1) wl += __shfl_xor(wl, d);
    size_t gr = (size_t)(r0 + lr);
    if (lane == 0) logits[gr] = wl;
    vm[gr * 64 + lane] = vl;
}

// ---------------- attention partials: 16 blocks/head, 64 slots/block ----------------
__global__ __launch_bounds__(256) void attend_part(const float* __restrict__ logits,
                                                   const float* __restrict__ vm,
                                                   float* __restrict__ part) {
    int b = blockIdx.x;
    int h = b >> 4;
    int s0 = (b & 15) * 64;
    int tid = threadIdx.x;
    __shared__ float els[64];
    __shared__ float pr[4][64];
    __shared__ float lmax_s, lsum_s;
    if (tid < 64) {
        float lg = logits[h * 1024 + s0 + tid];
        float m = lg;
        for (int d = 32; d; d >>= 1) m = fmaxf(m, __shfl_xor(m, d));
        float e = __expf(lg - m);
        els[tid] = e;
        float s = e;
        for (int d = 32; d; d >>= 1) s += __shfl_xor(s, d);
        if (tid == 0) { lmax_s = m; lsum_s = s; }
    }
    __syncthreads();
    int dd = tid & 63, g = tid >> 6;
    float acc = 0;
    for (int s = g; s < 64; s += 4)
        acc += els[s] * vm[((size_t)h * 1024 + s0 + s) * 64 + dd];
    pr[g][dd] = acc;
    __syncthreads();
    if (tid < 64) {
        float pv = pr[0][tid] + pr[1][tid] + pr[2][tid] + pr[3][tid];
        part[b * 66 + 2 + tid] = pv;
        if (tid == 0) { part[b * 66] = lmax_s; part[b * 66 + 1] = lsum_s; }
    }
}

// ---------------- final MLP head (absorbs attend_final merge + m_out GEMV) ----------------
__device__ __forceinline__ float block_sum_256(float v, float* red) {
    int tid = threadIdx.x;
    red[tid] = v;
    __syncthreads();
    for (int d = 128; d; d >>= 1) { if (tid < d) red[tid] += red[tid + d]; __syncthreads(); }
    float r = red[0];
    __syncthreads();
    return r;
}

__global__ __launch_bounds__(256) void head_kernel(
    const float* __restrict__ x, const int* __restrict__ index_p,
    const int* __restrict__ inp_types, const float* __restrict__ log_return,
    const float* __restrict__ emb, const float* __restrict__ qv,
    const float* __restrict__ apart, const float* __restrict__ mfx_w,
    const float* __restrict__ mfx_b, const float* __restrict__ f1_w,
    const float* __restrict__ n1_w, const float* __restrict__ n1_b,
    const float* __restrict__ f2_w, const float* __restrict__ n2_w,
    const float* __restrict__ n2_b, const float* __restrict__ f3_w,
    const float* __restrict__ f3_b, float* __restrict__ out) {
    __shared__ float feat[273];
    __shared__ float h1[512];
    __shared__ float h2[256];
    __shared__ float red[256];
    __shared__ float l3[3];
    __shared__ float mv_s[256];
    __shared__ float mpart[1024];
    __shared__ float m_out_s[64];
    int r = blockIdx.x, tid = threadIdx.x;
    int idx = index_p[0];
    // --- attend_final merge (redundant per block, ~16k MAC: removes a serial dispatch) ---
    {
        int h = tid >> 6, dd = tid & 63;
        float gmax = -1e30f;
#pragma unroll
        for (int p = 0; p < 16; ++p) gmax = fmaxf(gmax, apart[(h * 16 + p) * 66]);
        float total = 0.f, acc = 0.f;
#pragma unroll
        for (int p = 0; p < 16; ++p) {
            float sc = __expf(apart[(h * 16 + p) * 66] - gmax);
            total += apart[(h * 16 + p) * 66 + 1] * sc;
            acc += apart[(h * 16 + p) * 66 + 2 + dd] * sc;
        }
        mv_s[h * 64 + dd] = acc / total;
    }
    __syncthreads();
    {
        int og = tid & 15, kc = tid >> 4;
        int j4 = og * 4;
        f32x4 a = {0.f, 0.f, 0.f, 0.f};
        for (int ci = 0; ci < 16; ++ci) {
            int c = kc * 16 + ci;
            float4 w = *(const float4*)(mfx_w + (size_t)c * 64 + j4);
            float mc = mv_s[c];
            a[0] += mc * w.x; a[1] += mc * w.y; a[2] += mc * w.z; a[3] += mc * w.w;
        }
#pragma unroll
        for (int i = 0; i < 4; ++i) mpart[kc * 64 + j4 + i] = a[i];
    }
    __syncthreads();
    if (tid < 64) {
        float s = mfx_b[tid];
#pragma unroll
        for (int kc = 0; kc < 16; ++kc) s += mpart[kc * 64 + tid];
        m_out_s[tid] = s;
    }
    __syncthreads();
    // --- feature assembly ---
    for (int i = tid; i < 273; i += 256) {
        float val;
        if (i < 128) val = x[(size_t)idx * 128 + i];
        else if (i < 144) val = emb[inp_types[r] * 16 + (i - 128)];
        else if (i == 144) val = log_return[r];
        else if (i < 209) val = qv[64 + (i - 145)];
        else val = m_out_s[i - 209];
        feat[i] = val;
    }
    __syncthreads();
    float a0 = 0, a1 = 0;
    for (int c = 0; c < 273; ++c) {
        float f = feat[c];
        a0 += f * f1_w[c * 512 + tid];
        a1 += f * f1_w[c * 512 + tid + 256];
    }
    float mu = block_sum_256(a0 + a1, red) / 512.f;
    float c0 = a0 - mu, c1 = a1 - mu;
    float var = block_sum_256(c0 * c0 + c1 * c1, red) / 512.f;
    float inv = rsqrtf(var + 1e-5f);
    h1[tid] = fmaxf(c0 * inv * n1_w[tid] + n1_b[tid], 0.f);
    h1[tid + 256] = fmaxf(c1 * inv * n1_w[tid + 256] + n1_b[tid + 256], 0.f);
    __syncthreads();
    float b0 = 0;
    for (int c = 0; c < 512; ++c) b0 += h1[c] * f2_w[c * 256 + tid];
    float mu2 = block_sum_256(b0, red) / 256.f;
    float cc = b0 - mu2;
    float var2 = block_sum_256(cc * cc, red) / 256.f;
    float inv2 = rsqrtf(var2 + 1e-5f);
    h2[tid] = fmaxf(cc * inv2 * n2_w[tid] + n2_b[tid], 0.f);
    __syncthreads();
    if (tid < 3) {
        float a = f3_b[tid];
        for (int c = 0; c < 256; ++c) a += h2[c] * f3_w[c * 3 + tid];
        l3[tid] = a;
    }
    __syncthreads();
    if (tid < 3) {
        float mx = fmaxf(l3[0], fmaxf(l3[1], l3[2]));
        float s = __expf(l3[0] - mx) + __expf(l3[1] - mx) + __expf(l3[2] - mx);
        out[r * 3 + tid] = __expf(l3[tid] - mx) / s;
    }
}

extern "C" void kernel_launch(void* const* d_in, const int* in_sizes, int n_in,
                              void* d_out, int out_size, void* d_ws, size_t ws_size,
                              hipStream_t stream) {
    const float* x = (const float*)d_in[0];
    const int* ei = (const int*)d_in[1];
    const int* index_p = (const int*)d_in[2];
    const int* inp_types = (const int*)d_in[3];
    const float* log_return = (const float*)d_in[4];
    const float* t1 = (const float*)d_in[5];
    const float* W1l = (const float*)d_in[6];
    const float* W1r = (const float*)d_in[7];
    const float* ln1g_w = (const float*)d_in[8];
    const float* ln1g_b = (const float*)d_in[9];
    const float* t2 = (const float*)d_in[10];
    const float* W2l = (const float*)d_in[11];
    const float* W2r = (const float*)d_in[12];
    const float* ln2g_w = (const float*)d_in[13];
    const float* ln2g_b = (const float*)d_in[14];
    // d_in[15] mp_k, d_in[16] mp_conv: provably unused (K=1 makes S==1)
    const float* mp_lin = (const float*)d_in[17];
    const float* fxg_w = (const float*)d_in[18];
    const float* fxg_b = (const float*)d_in[19];
    const float* emb = (const float*)d_in[20];
    const float* fk_w = (const float*)d_in[21];
    const float* fk_b = (const float*)d_in[22];
    const float* fv_w = (const float*)d_in[23];
    const float* fv_b = (const float*)d_in[24];
    const float* mem = (const float*)d_in[25];
    const float* mfk_w = (const float*)d_in[26];
    const float* mfk_b = (const float*)d_in[27];
    const float* mfv_w = (const float*)d_in[28];
    const float* mfv_b = (const float*)d_in[29];
    const float* mfx_w = (const float*)d_in[30];
    const float* mfx_b = (const float*)d_in[31];
    const float* f1_w = (const float*)d_in[32];
    const float* n1_w = (const float*)d_in[33];
    const float* n1_b = (const float*)d_in[34];
    const float* f2_w = (const float*)d_in[35];
    const float* n2_w = (const float*)d_in[36];
    const float* n2_b = (const float*)d_in[37];
    const float* f3_w = (const float*)d_in[38];
    const float* f3_b = (const float*)d_in[39];
    float* out = (float*)d_out;

    int n = in_sizes[0] / 128;
    int E = in_sizes[1] / 2;
    int T = in_sizes[3];
    const int* src = ei;
    const int* dst = ei + E;

    char* w = (char*)d_ws;
    auto alloc = [&](size_t bytes) {
        char* p = w;
        w += (bytes + 255) & ~(size_t)255;
        return p;
    };
    int* counts = (int*)alloc((size_t)n * 4);
    int* off = (int*)alloc((size_t)(n + 1) * 4);
    int* srcs = (int*)alloc((size_t)E * 4);
    unsigned short* xb = (unsigned short*)alloc((size_t)n * 128 * 2);
    unsigned short* agg1b = (unsigned short*)alloc((size_t)n * 128 * 2);
    unsigned short* z1b = (unsigned short*)alloc((size_t)n * 512 * 2);
    unsigned short* agg2b = (unsigned short*)alloc((size_t)n * 512 * 2);
    unsigned short* z2b = (unsigned short*)alloc((size_t)n * 256 * 2);
    double* partd = (double*)alloc(2048 * 2 * 8);
    float* cspartT = (float*)alloc(256 * 64 * 4);
    float* qv = (float*)alloc(128 * 4);
    float* logits = (float*)alloc((size_t)4 * 1024 * 4);
    float* vm = (float*)alloc((size_t)4 * 1024 * 64 * 4);
    float* apart = (float*)alloc(64 * 66 * 4);
    unsigned short* Bt1 = (unsigned short*)alloc((size_t)512 * 256 * 2);
    unsigned short* Bt2 = (unsigned short*)alloc((size_t)256 * 1024 * 2);

    int nblk_e = (E + 255) / 256;
    int mblk64 = (n + 63) / 64;

    // CSR build + fused prologue (count/cast/pack are independent)
    hipMemsetAsync(counts, 0, (size_t)n * 4, stream);
    prep_kernel<<<nblk_e, 256, 0, stream>>>(dst, E, counts, x, xb, (size_t)n * 128 / 4,
                                            W1l, W1r, Bt1, W2l, W2r, Bt2);
    scan_kernel<20><<<1, 1024, 0, stream>>>(counts, off, n);  // also zeroes counts
    fill_kernel<<<nblk_e, 256, 0, stream>>>(src, dst, E, off, counts, srcs);

    // SAGE layer 1: z1 = agg1@W1l + x@W1r  (fused MFMA GEMM + stats)
    agg128<<<(n + 3) / 4, 256, 0, stream>>>(xb, t1, off, srcs, agg1b, n);
    gemm_dual_mfma3<<<dim3(2, mblk64), 256, 0, stream>>>(agg1b, xb, Bt1, z1b, partd, n, 512, 128, 128);
    ln_relu_ip<512><<<1024, 256, 0, stream>>>(z1b, ln1g_w, ln1g_b, partd, 2 * mblk64,
                                              1.0f / ((float)n * 512.f), (size_t)n * 512);

    // SAGE layer 2: z2 = agg2@W2l + z1@W2r  (channel-split aggregation)
    agg512s<<<dim3((n + 3) / 4, 2), 256, 0, stream>>>(z1b, t2, off, srcs, agg2b, n);
    gemm_dual_mfma3<<<dim3(1, mblk64), 256, 0, stream>>>(agg2b, z1b, Bt2, z2b, partd, n, 256, 512, 512);

    // LN2+ReLU fused into MemPooling column sum (z2 post-LN has no other consumer)
    ln_colsum<<<64, 256, 0, stream>>>(z2b, ln2g_w, ln2g_b, partd, mblk64,
                                      1.0f / ((float)n * 256.f), n, cspartT);
    zqv_kernel<<<1, 256, 0, stream>>>(cspartT, mp_lin, fxg_w, fxg_b, fk_w, fk_b, fv_w, fv_b, qv);

    // MultiHeadMemory (parallel softmax-attention; final merge fused into head)
    mem_kv_logit<<<1024, 256, 0, stream>>>(mem, mfk_w, mfk_b, mfv_w, mfv_b, qv, logits, vm);
    attend_part<<<64, 256, 0, stream>>>(logits, vm, apart);

    // head (includes attend_final merge + m_out GEMV, redundant per block)
    head_kernel<<<T, 256, 0, stream>>>(x, index_p, inp_types, log_return, emb, qv, apart,
                                       mfx_w, mfx_b, f1_w, n1_w, n1_b, f2_w, n2_w, n2_b,
                                       f3_w, f3_b, out);
}